// Round 1
// baseline (773.600 us; speedup 1.0000x reference)
//
#include <hip/hip_runtime.h>
#include <math.h>

#define Bn 8
#define Cn 64
#define Hn 96
#define Wn 96
#define HWn (Hn*Wn)
#define OCn 64
#define Kn 9
#define OFFCn 27
#define NPIX (Bn*HWn)   // 73728 = 1152 * 64 exactly

__global__ __launch_bounds__(64) void dcn_fused(
    const float* __restrict__ x,
    const float* __restrict__ w_off,
    const float* __restrict__ b_off,
    const float* __restrict__ weight,
    const float* __restrict__ bias,
    float* __restrict__ out)
{
    // NPIX is an exact multiple of grid*block -> no bounds check, keeps
    // control flow uniform so weight loads stay scalar (s_load).
    const int p  = blockIdx.x * 64 + threadIdx.x;
    const int b  = p / HWn;
    const int hw = p % HWn;
    const int ho = hw / Wn;
    const int wo = hw % Wn;

    const float* xb = x + b * (Cn * HWn);

    // ---------------- Phase 1: offset conv (3x3, pad 1) -> om[27] ----------------
    float om[OFFCn];
#pragma unroll
    for (int j = 0; j < OFFCn; ++j) om[j] = b_off[j];

    int   toff[Kn];
    float tval[Kn];
#pragma unroll
    for (int ki = 0; ki < Kn; ++ki) {
        const int dy = ki / 3 - 1, dx = ki % 3 - 1;
        const int yy = ho + dy, xx = wo + dx;
        const bool v = (yy >= 0) && (yy < Hn) && (xx >= 0) && (xx < Wn);
        const int yyc = min(max(yy, 0), Hn - 1);
        const int xxc = min(max(xx, 0), Wn - 1);
        toff[ki] = yyc * Wn + xxc;
        tval[ki] = v ? 1.0f : 0.0f;
    }

    for (int c = 0; c < Cn; ++c) {
        const float* xc = xb + c * HWn;
        float xk[Kn];
#pragma unroll
        for (int ki = 0; ki < Kn; ++ki)
            xk[ki] = xc[toff[ki]] * tval[ki];   // zero-pad via multiply (branchless)

        const float* wc = w_off + c * Kn;       // w_off[och][c][0..8] contiguous in ki
#pragma unroll
        for (int och = 0; och < OFFCn; ++och) {
            const float* wp = wc + och * (Cn * Kn);
            float a = om[och];
#pragma unroll
            for (int ki = 0; ki < Kn; ++ki)
                a = fmaf(xk[ki], wp[ki], a);
            om[och] = a;
        }
    }

    // ---------------- Phase 1.5: per-k sampling parameters ----------------
    float pw0[Kn], pw1[Kn], pw2[Kn], pw3[Kn];
    int   pa[Kn], pdx[Kn], pdyw[Kn];
#pragma unroll
    for (int ki = 0; ki < Kn; ++ki) {
        const float py = om[ki]      + (float)(ki / 3 + ho - 1);
        const float px = om[Kn + ki] + (float)(ki % 3 + wo - 1);
        const float m  = 1.0f / (1.0f + __expf(-om[2 * Kn + ki]));

        const float y0f = floorf(py), x0f = floorf(px);
        const float ly = py - y0f, lx = px - x0f;
        const int iy0 = (int)y0f, ix0 = (int)x0f;
        const int iy1 = iy0 + 1,  ix1 = ix0 + 1;

        const float vy0 = (iy0 >= 0 && iy0 < Hn) ? 1.0f : 0.0f;
        const float vy1 = (iy1 >= 0 && iy1 < Hn) ? 1.0f : 0.0f;
        const float vx0 = (ix0 >= 0 && ix0 < Wn) ? 1.0f : 0.0f;
        const float vx1 = (ix1 >= 0 && ix1 < Wn) ? 1.0f : 0.0f;

        const int iy0c = min(max(iy0, 0), Hn - 1);
        const int iy1c = min(max(iy1, 0), Hn - 1);
        const int ix0c = min(max(ix0, 0), Wn - 1);
        const int ix1c = min(max(ix1, 0), Wn - 1);

        pw0[ki] = m * (1.0f - ly) * (1.0f - lx) * vy0 * vx0;
        pw1[ki] = m * (1.0f - ly) * lx          * vy0 * vx1;
        pw2[ki] = m * ly          * (1.0f - lx) * vy1 * vx0;
        pw3[ki] = m * ly          * lx          * vy1 * vx1;
        pa[ki]   = iy0c * Wn + ix0c;
        pdx[ki]  = ix1c - ix0c;          // 0 or 1
        pdyw[ki] = (iy1c - iy0c) * Wn;   // 0 or Wn
    }

    // ---------------- Phase 2: sample + 64x(64x9) contraction ----------------
    float acc[OCn];
#pragma unroll
    for (int oc = 0; oc < OCn; ++oc) acc[oc] = bias[oc];

    for (int c = 0; c < Cn; ++c) {
        const float* xc = xb + c * HWn;
        float s[Kn];
#pragma unroll
        for (int ki = 0; ki < Kn; ++ki) {
            const float* bp = xc + pa[ki];
            const float v00 = bp[0];
            const float v01 = bp[pdx[ki]];
            const float v10 = bp[pdyw[ki]];
            const float v11 = bp[pdyw[ki] + pdx[ki]];
            s[ki] = pw0[ki] * v00 + pw1[ki] * v01 + pw2[ki] * v10 + pw3[ki] * v11;
        }

        const float* wc = weight + c * Kn;      // weight[oc][c][0..8] contiguous in ki
#pragma unroll
        for (int oc = 0; oc < OCn; ++oc) {
            const float* wp = wc + oc * (Cn * Kn);
            float a = acc[oc];
#pragma unroll
            for (int ki = 0; ki < Kn; ++ki)
                a = fmaf(s[ki], wp[ki], a);
            acc[oc] = a;
        }
    }

    float* ob = out + b * (OCn * HWn) + hw;
#pragma unroll
    for (int oc = 0; oc < OCn; ++oc)
        ob[oc * HWn] = acc[oc];
}

extern "C" void kernel_launch(void* const* d_in, const int* in_sizes, int n_in,
                              void* d_out, int out_size, void* d_ws, size_t ws_size,
                              hipStream_t stream) {
    const float* x      = (const float*)d_in[0];
    const float* w_off  = (const float*)d_in[1];
    const float* b_off  = (const float*)d_in[2];
    const float* weight = (const float*)d_in[3];
    const float* bias   = (const float*)d_in[4];
    float* out = (float*)d_out;

    dim3 grid(NPIX / 64);
    dim3 block(64);
    hipLaunchKernelGGL(dcn_fused, grid, block, 0, stream,
                       x, w_off, b_off, weight, bias, out);
}